// Round 1
// baseline (2552.597 us; speedup 1.0000x reference)
//
#include <hip/hip_runtime.h>
#include <math.h>

#define HID 128
#define NRAYS 4096
#define TP 64   // points per MLP tile

__device__ __forceinline__ float sp_f(float x){        // jax.nn.softplus, stable
  return fmaxf(x, 0.0f) + log1pf(expf(-fabsf(x)));
}
__device__ __forceinline__ float sg_f(float x){        // sigmoid
  return 1.0f / (1.0f + expf(-x));
}

// ---------------------------------------------------------------- transpose W2
__global__ void k_transpose(const float* __restrict__ W2, float* __restrict__ W2T){
  int idx = blockIdx.x*256 + threadIdx.x;
  if (idx < HID*HID){
    int k = idx >> 7, n = idx & 127;
    W2T[n*HID + k] = W2[k*HID + n];
  }
}

// ---------------------------------------------------------------- initial z + pts
__global__ void k_init(const float* __restrict__ rays_o, const float* __restrict__ rays_d,
                       const float* __restrict__ nearv, const float* __restrict__ farv,
                       float* __restrict__ z_buf, float* __restrict__ pts){
  int idx = blockIdx.x*256 + threadIdx.x;
  if (idx >= NRAYS*64) return;
  int ray = idx >> 6, j = idx & 63;
  float nr = nearv[ray];
  float z = nr + (farv[ray] - nr) * ((float)j / 63.0f);
  z_buf[ray*128 + j] = z;
  pts[idx*3+0] = rays_o[ray*3+0] + rays_d[ray*3+0]*z;
  pts[idx*3+1] = rays_o[ray*3+1] + rays_d[ray*3+1]*z;
  pts[idx*3+2] = rays_o[ray*3+2] + rays_d[ray*3+2]*z;
}

// ---------------------------------------------------------------- MLP forward
// grid = P/64 blocks, 256 threads. LDS: W2 64KB + h1 32KB (+small) -> 1 block/CU.
__global__ __launch_bounds__(256) void k_mlp_fwd(
    const float* __restrict__ pts,
    const float* __restrict__ W1, const float* __restrict__ b1,
    const float* __restrict__ W2, const float* __restrict__ b2,
    const float* __restrict__ W3, const float* __restrict__ b3,
    float* __restrict__ sdf_out){
  __shared__ float sW[HID*HID];   // W2 [k][n]
  __shared__ float sH[HID*TP];    // h1 [k][p]
  __shared__ float sX[TP*3];
  __shared__ float sW1[3*HID];
  __shared__ float sB1[HID], sB2[HID], sW3[HID];
  __shared__ float sAcc[TP];
  const int tid = threadIdx.x;
  const int q0  = blockIdx.x * TP;
  for (int i = tid; i < HID*HID; i += 256) sW[i] = W2[i];
  for (int i = tid; i < 3*HID;  i += 256) sW1[i] = W1[i];
  if (tid < HID){ sB1[tid] = b1[tid]; sB2[tid] = b2[tid]; sW3[tid] = W3[tid]; }
  for (int i = tid; i < TP*3; i += 256) sX[i] = pts[q0*3 + i];
  if (tid < TP) sAcc[tid] = b3[0];
  __syncthreads();
  // layer 1
  for (int i = tid; i < HID*TP; i += 256){
    int k = i >> 6, p = i & 63;
    float pre = sB1[k] + sX[p*3+0]*sW1[k] + sX[p*3+1]*sW1[HID+k] + sX[p*3+2]*sW1[2*HID+k];
    sH[k*TP + p] = sp_f(pre);
  }
  __syncthreads();
  // layer 2: thread tile 4 points x 8 neurons
  const int pg = tid >> 4, ng = tid & 15;
  const int p0 = pg*4, n0 = ng*8;
  float acc[4][8];
  #pragma unroll
  for (int i = 0; i < 4; i++)
    #pragma unroll
    for (int j = 0; j < 8; j++) acc[i][j] = sB2[n0+j];
  for (int k = 0; k < HID; k++){
    const float4 hv = *reinterpret_cast<const float4*>(&sH[k*TP + p0]);
    const float4 w0 = *reinterpret_cast<const float4*>(&sW[k*HID + n0]);
    const float4 w1 = *reinterpret_cast<const float4*>(&sW[k*HID + n0 + 4]);
    const float h[4] = {hv.x, hv.y, hv.z, hv.w};
    const float w[8] = {w0.x, w0.y, w0.z, w0.w, w1.x, w1.y, w1.z, w1.w};
    #pragma unroll
    for (int i = 0; i < 4; i++)
      #pragma unroll
      for (int j = 0; j < 8; j++) acc[i][j] = fmaf(h[i], w[j], acc[i][j]);
  }
  // layer 3 partial reduction
  float part[4] = {0.f,0.f,0.f,0.f};
  #pragma unroll
  for (int i = 0; i < 4; i++)
    #pragma unroll
    for (int j = 0; j < 8; j++) part[i] += sp_f(acc[i][j]) * sW3[n0+j];
  #pragma unroll
  for (int i = 0; i < 4; i++) atomicAdd(&sAcc[p0+i], part[i]);
  __syncthreads();
  if (tid < TP) sdf_out[q0 + tid] = sAcc[tid];
}

// ---------------------------------------------------------------- scatters
__global__ void k_scatter_init(const float* __restrict__ sdf_tmp, float* __restrict__ sdf_buf){
  int idx = blockIdx.x*256 + threadIdx.x;
  if (idx >= NRAYS*64) return;
  sdf_buf[(idx >> 6)*128 + (idx & 63)] = sdf_tmp[idx];
}
__global__ void k_scatter_new(const float* __restrict__ sdf_tmp, const int* __restrict__ slots,
                              float* __restrict__ sdf_buf){
  int idx = blockIdx.x*256 + threadIdx.x;
  if (idx >= NRAYS*16) return;
  sdf_buf[(idx >> 4)*128 + slots[idx]] = sdf_tmp[idx];
}

// ---------------------------------------------------------------- upsample (one wave per ray)
__global__ __launch_bounds__(64) void k_upsample(
      const float* __restrict__ rays_o, const float* __restrict__ rays_d,
      float* __restrict__ z_buf, float* __restrict__ sdf_buf,
      float* __restrict__ pts_new, int* __restrict__ slots,
      int S, float inv_s, int last){
  __shared__ float z[128], sd[128], rad[128], cosv[128], alf[128], wv[128], cdf[129], nz[16];
  __shared__ int slt[16];
  const int ray = blockIdx.x;
  const int l   = threadIdx.x;
  const float ox = rays_o[ray*3], oy = rays_o[ray*3+1], oz = rays_o[ray*3+2];
  const float dx = rays_d[ray*3], dy = rays_d[ray*3+1], dz = rays_d[ray*3+2];
  for (int j = l; j < S; j += 64){
    float zz = z_buf[ray*128+j];
    z[j]  = zz;
    sd[j] = sdf_buf[ray*128+j];
    float px = ox+dx*zz, py = oy+dy*zz, pz = oz+dz*zz;
    rad[j] = sqrtf(px*px + py*py + pz*pz);
  }
  __syncthreads();
  for (int j = l; j < S-1; j += 64)
    cosv[j] = (sd[j+1]-sd[j]) / (z[j+1]-z[j] + 1e-5f);
  __syncthreads();
  for (int j = l; j < S-1; j += 64){
    float cv = fminf((j > 0) ? cosv[j-1] : 0.0f, cosv[j]);
    cv = fminf(fmaxf(cv, -1000.0f), 0.0f);
    float inside = (rad[j] < 1.0f || rad[j+1] < 1.0f) ? 1.0f : 0.0f;
    cv *= inside;
    float mid  = 0.5f*(sd[j]+sd[j+1]);
    float dist = z[j+1]-z[j];
    float e = sg_f((mid - cv*dist*0.5f)*inv_s);
    float f = sg_f((mid + cv*dist*0.5f)*inv_s);
    alf[j] = (e - f + 1e-5f) / (e + 1e-5f);
  }
  __syncthreads();
  if (l == 0){
    float T = 1.0f, wsum = 0.0f;
    for (int j = 0; j < S-1; j++){
      float w = alf[j]*T + 1e-5f;   // weights = alpha*trans + 1e-5
      wv[j] = w; wsum += w;
      T *= (1.0f - alf[j] + 1e-7f);
    }
    cdf[0] = 0.0f;
    float c = 0.0f;
    for (int j = 0; j < S-1; j++){ c += wv[j]/wsum; cdf[j+1] = c; }
  }
  __syncthreads();
  if (l < 16){
    float u = 0.03125f + 0.0625f*(float)l;   // linspace(1/32, 31/32, 16)
    int idx = 0;
    while (idx < S && cdf[idx] <= u) idx++;  // searchsorted side='right'
    int below = idx - 1; if (below < 0) below = 0;
    int above = (idx < S-1) ? idx : (S-1);
    float cb = cdf[below], ca = cdf[above];
    float den = ca - cb; if (den < 1e-5f) den = 1.0f;
    float t = (u - cb) / den;
    nz[l] = z[below] + t*(z[above] - z[below]);
  }
  __syncthreads();
  if (l == 0){
    // stable in-place merge from the back (old-before-new on ties)
    int i = S-1, j = 15;
    for (int dst = S+15; dst >= 0; --dst){
      bool takeOld = (j < 0) || (i >= 0 && z[i] > nz[j]);
      if (takeOld){ z[dst] = z[i]; sd[dst] = sd[i]; i--; }
      else        { z[dst] = nz[j]; slt[j] = dst; j--; }
    }
  }
  __syncthreads();
  for (int j = l; j < S+16; j += 64){
    z_buf[ray*128+j]  = z[j];
    sdf_buf[ray*128+j] = sd[j];
  }
  if (!last && l < 16){
    slots[ray*16+l] = slt[l];
    float zz = nz[l];
    pts_new[(ray*16+l)*3+0] = ox + dx*zz;
    pts_new[(ray*16+l)*3+1] = oy + dy*zz;
    pts_new[(ray*16+l)*3+2] = oz + dz*zz;
  }
}

// ---------------------------------------------------------------- final mid-point pts
__global__ void k_prep(const float* __restrict__ rays_o, const float* __restrict__ rays_d,
                       const float* __restrict__ z_buf, float* __restrict__ pts){
  int idx = blockIdx.x*256 + threadIdx.x;
  if (idx >= NRAYS*128) return;
  int ray = idx >> 7, s = idx & 127;
  float z = z_buf[idx];
  float d = (s < 127) ? (z_buf[idx+1] - z) : 0.03125f;   // SAMPLE_DIST = 2/64
  float mid = z + 0.5f*d;
  pts[idx*3+0] = rays_o[ray*3+0] + rays_d[ray*3+0]*mid;
  pts[idx*3+1] = rays_o[ray*3+1] + rays_d[ray*3+1]*mid;
  pts[idx*3+2] = rays_o[ray*3+2] + rays_d[ray*3+2]*mid;
}

// ---------------------------------------------------------------- MLP forward + input-gradient
__global__ __launch_bounds__(256) void k_mlp_fwdbwd(
    const float* __restrict__ pts,
    const float* __restrict__ W1, const float* __restrict__ b1,
    const float* __restrict__ W2, const float* __restrict__ b2,
    const float* __restrict__ W3, const float* __restrict__ b3,
    const float* __restrict__ W2T,
    float* __restrict__ sdf_out, float* __restrict__ grad_out){
  __shared__ float sW[HID*HID];   // W2 in phase A, W2T in phase C
  __shared__ float sB[HID*TP];    // h1 [k][p] in phase A, g2 [n][p] in phase C
  __shared__ float sX[TP*3];
  __shared__ float sW1[3*HID];
  __shared__ float sB1[HID], sB2[HID], sW3[HID];
  __shared__ float sSdf[TP];
  __shared__ float sG[TP*3];
  const int tid = threadIdx.x;
  const int q0  = blockIdx.x * TP;
  for (int i = tid; i < HID*HID; i += 256) sW[i] = W2[i];
  for (int i = tid; i < 3*HID;  i += 256) sW1[i] = W1[i];
  if (tid < HID){ sB1[tid] = b1[tid]; sB2[tid] = b2[tid]; sW3[tid] = W3[tid]; }
  for (int i = tid; i < TP*3; i += 256){ sX[i] = pts[q0*3 + i]; sG[i] = 0.0f; }
  if (tid < TP) sSdf[tid] = b3[0];
  __syncthreads();
  // layer 1
  for (int i = tid; i < HID*TP; i += 256){
    int k = i >> 6, p = i & 63;
    float pre = sB1[k] + sX[p*3+0]*sW1[k] + sX[p*3+1]*sW1[HID+k] + sX[p*3+2]*sW1[2*HID+k];
    sB[k*TP + p] = sp_f(pre);
  }
  __syncthreads();
  // layer 2 forward: 4p x 8n tile
  const int pg = tid >> 4, ng = tid & 15;
  const int p0 = pg*4, n0 = ng*8;
  float acc[4][8];
  #pragma unroll
  for (int i = 0; i < 4; i++)
    #pragma unroll
    for (int j = 0; j < 8; j++) acc[i][j] = sB2[n0+j];
  for (int k = 0; k < HID; k++){
    const float4 hv = *reinterpret_cast<const float4*>(&sB[k*TP + p0]);
    const float4 w0 = *reinterpret_cast<const float4*>(&sW[k*HID + n0]);
    const float4 w1 = *reinterpret_cast<const float4*>(&sW[k*HID + n0 + 4]);
    const float h[4] = {hv.x, hv.y, hv.z, hv.w};
    const float w[8] = {w0.x, w0.y, w0.z, w0.w, w1.x, w1.y, w1.z, w1.w};
    #pragma unroll
    for (int i = 0; i < 4; i++)
      #pragma unroll
      for (int j = 0; j < 8; j++) acc[i][j] = fmaf(h[i], w[j], acc[i][j]);
  }
  __syncthreads();   // everyone done reading sB (h1) and sW (W2)
  // sdf partials + g2 = sigmoid(pre2)*W3 into sB; reload sW = W2T
  {
    float part[4] = {0.f,0.f,0.f,0.f};
    #pragma unroll
    for (int i = 0; i < 4; i++)
      #pragma unroll
      for (int j = 0; j < 8; j++){
        float pre2 = acc[i][j];
        part[i] += sp_f(pre2) * sW3[n0+j];
        sB[(n0+j)*TP + (p0+i)] = sg_f(pre2) * sW3[n0+j];
      }
    #pragma unroll
    for (int i = 0; i < 4; i++) atomicAdd(&sSdf[p0+i], part[i]);
  }
  for (int i = tid; i < HID*HID; i += 256) sW[i] = W2T[i];
  __syncthreads();
  // phase C: dh1[k][p] = sum_n W2T[n][k] * g2[n][p]; tile 4p x 8k
  const int k0 = ng*8;
  float accD[4][8];
  #pragma unroll
  for (int i = 0; i < 4; i++)
    #pragma unroll
    for (int j = 0; j < 8; j++) accD[i][j] = 0.0f;
  for (int n = 0; n < HID; n++){
    const float4 gv = *reinterpret_cast<const float4*>(&sB[n*TP + p0]);
    const float4 w0 = *reinterpret_cast<const float4*>(&sW[n*HID + k0]);
    const float4 w1 = *reinterpret_cast<const float4*>(&sW[n*HID + k0 + 4]);
    const float g[4] = {gv.x, gv.y, gv.z, gv.w};
    const float w[8] = {w0.x, w0.y, w0.z, w0.w, w1.x, w1.y, w1.z, w1.w};
    #pragma unroll
    for (int i = 0; i < 4; i++)
      #pragma unroll
      for (int j = 0; j < 8; j++) accD[i][j] = fmaf(g[i], w[j], accD[i][j]);
  }
  // dp1 = dh1 * sigmoid(pre1) (recompute pre1 from x), then grad = W1 @ dp1
  #pragma unroll
  for (int i = 0; i < 4; i++){
    float x0 = sX[(p0+i)*3+0], x1 = sX[(p0+i)*3+1], x2 = sX[(p0+i)*3+2];
    float gx = 0.f, gy = 0.f, gz = 0.f;
    #pragma unroll
    for (int j = 0; j < 8; j++){
      int k = k0 + j;
      float w1a = sW1[k], w1b = sW1[HID+k], w1c = sW1[2*HID+k];
      float pre1 = sB1[k] + x0*w1a + x1*w1b + x2*w1c;
      float d = accD[i][j] * sg_f(pre1);
      gx = fmaf(w1a, d, gx); gy = fmaf(w1b, d, gy); gz = fmaf(w1c, d, gz);
    }
    atomicAdd(&sG[(p0+i)*3+0], gx);
    atomicAdd(&sG[(p0+i)*3+1], gy);
    atomicAdd(&sG[(p0+i)*3+2], gz);
  }
  __syncthreads();
  if (tid < TP) sdf_out[q0 + tid] = sSdf[tid];
  for (int i = tid; i < TP*3; i += 256) grad_out[q0*3 + i] = sG[i];
}

// ---------------------------------------------------------------- render (one thread per ray)
__global__ void k_render(const float* __restrict__ z_buf, const float* __restrict__ sdf_mid,
                         const float* __restrict__ rays_d, const float* __restrict__ grad,
                         const float* __restrict__ variance, float* __restrict__ depth_out){
  int ray = blockIdx.x*64 + threadIdx.x;
  if (ray >= NRAYS) return;
  float inv_s = expf(10.0f * variance[0]);
  inv_s = fminf(fmaxf(inv_s, 1e-6f), 1e6f);
  const float dx = rays_d[ray*3], dy = rays_d[ray*3+1], dz = rays_d[ray*3+2];
  float T = 1.0f, depth = 0.0f;
  float zc = z_buf[ray*128];
  for (int s = 0; s < 128; s++){
    int idx = ray*128 + s;
    float zn = (s < 127) ? z_buf[idx+1] : zc;
    float d  = (s < 127) ? (zn - zc) : 0.03125f;
    float sdf = sdf_mid[idx];
    float gx = grad[idx*3], gy = grad[idx*3+1], gz = grad[idx*3+2];
    float tc = dx*gx + dy*gy + dz*gz;
    float ic = -fmaxf(0.5f - 0.5f*tc, 0.0f);     // COS_ANNEAL_RATIO = 0
    float e = sg_f((sdf - ic*d*0.5f)*inv_s);
    float f = sg_f((sdf + ic*d*0.5f)*inv_s);
    float a = (e - f + 1e-5f) / (e + 1e-5f);
    a = fminf(fmaxf(a, 0.0f), 1.0f);
    depth += a*T*zc;
    T *= (1.0f - a + 1e-7f);
    zc = zn;
  }
  depth_out[ray] = depth;
}

// ---------------------------------------------------------------- launcher
extern "C" void kernel_launch(void* const* d_in, const int* in_sizes, int n_in,
                              void* d_out, int out_size, void* d_ws, size_t ws_size,
                              hipStream_t stream){
  (void)in_sizes; (void)n_in; (void)out_size; (void)ws_size;
  const float* rays_o = (const float*)d_in[0];
  const float* rays_d = (const float*)d_in[1];
  const float* nearv  = (const float*)d_in[2];
  const float* farv   = (const float*)d_in[3];
  const float* W1 = (const float*)d_in[4];
  const float* b1 = (const float*)d_in[5];
  const float* W2 = (const float*)d_in[6];
  const float* b2 = (const float*)d_in[7];
  const float* W3 = (const float*)d_in[8];
  const float* b3 = (const float*)d_in[9];
  const float* variance = (const float*)d_in[10];

  float* ws      = (float*)d_ws;
  float* z_buf   = ws;                    // 4096*128
  float* sdf_buf = ws + 524288;           // 4096*128
  float* sdf_tmp = ws + 1048576;          // up to 524288
  float* W2T     = ws + 1572864;          // 16384
  int*   slots   = (int*)(ws + 1589248);  // 4096*16 ints

  float* out       = (float*)d_out;
  float* depth_out = out;
  float* grad_out  = out + NRAYS;         // 524288*3 floats
  float* pts       = grad_out;            // alias: pts staging lives in the grad region

  k_transpose<<<dim3(64), dim3(256), 0, stream>>>(W2, W2T);
  k_init<<<dim3(1024), dim3(256), 0, stream>>>(rays_o, rays_d, nearv, farv, z_buf, pts);
  k_mlp_fwd<<<dim3(4096), dim3(256), 0, stream>>>(pts, W1,b1,W2,b2,W3,b3, sdf_tmp);
  k_scatter_init<<<dim3(1024), dim3(256), 0, stream>>>(sdf_tmp, sdf_buf);

  for (int i = 0; i < 4; i++){
    int S = 64 + 16*i;
    float inv_s = (float)(64 << i);
    int last = (i == 3) ? 1 : 0;
    k_upsample<<<dim3(4096), dim3(64), 0, stream>>>(rays_o, rays_d, z_buf, sdf_buf,
                                                    pts, slots, S, inv_s, last);
    if (!last){
      k_mlp_fwd<<<dim3(1024), dim3(256), 0, stream>>>(pts, W1,b1,W2,b2,W3,b3, sdf_tmp);
      k_scatter_new<<<dim3(256), dim3(256), 0, stream>>>(sdf_tmp, slots, sdf_buf);
    }
  }

  k_prep<<<dim3(2048), dim3(256), 0, stream>>>(rays_o, rays_d, z_buf, pts);
  k_mlp_fwdbwd<<<dim3(8192), dim3(256), 0, stream>>>(pts, W1,b1,W2,b2,W3,b3, W2T,
                                                     sdf_tmp, grad_out);
  k_render<<<dim3(64), dim3(64), 0, stream>>>(z_buf, sdf_tmp, rays_d, grad_out,
                                              variance, depth_out);
}

// Round 2
// 1543.197 us; speedup vs baseline: 1.6541x; 1.6541x over previous
//
#include <hip/hip_runtime.h>
#include <math.h>

#define HID 128
#define NRAYS 4096
#define TP 64   // points per MLP tile (one per lane)

__device__ __forceinline__ float sp_f(float x){        // jax.nn.softplus, stable
  return fmaxf(x, 0.0f) + log1pf(expf(-fabsf(x)));
}
__device__ __forceinline__ float sg_f(float x){        // sigmoid
  return 1.0f / (1.0f + expf(-x));
}

// ---------------------------------------------------------------- transpose W2
__global__ void k_transpose(const float* __restrict__ W2, float* __restrict__ W2T){
  int idx = blockIdx.x*256 + threadIdx.x;
  if (idx < HID*HID){
    int k = idx >> 7, n = idx & 127;
    W2T[n*HID + k] = W2[k*HID + n];
  }
}

// ---------------------------------------------------------------- initial z + pts
__global__ void k_init(const float* __restrict__ rays_o, const float* __restrict__ rays_d,
                       const float* __restrict__ nearv, const float* __restrict__ farv,
                       float* __restrict__ z_buf, float* __restrict__ pts){
  int idx = blockIdx.x*256 + threadIdx.x;
  if (idx >= NRAYS*64) return;
  int ray = idx >> 6, j = idx & 63;
  float nr = nearv[ray];
  float z = nr + (farv[ray] - nr) * ((float)j / 63.0f);
  z_buf[ray*128 + j] = z;
  pts[idx*3+0] = rays_o[ray*3+0] + rays_d[ray*3+0]*z;
  pts[idx*3+1] = rays_o[ray*3+1] + rays_d[ray*3+1]*z;
  pts[idx*3+2] = rays_o[ray*3+2] + rays_d[ray*3+2]*z;
}

// ---------------------------------------------------------------- MLP forward
// Wave w owns neurons [32w,32w+32); lane owns one point. W1/W2/W3/biases are
// wave-uniform -> scalar (s_load) operands. LDS only holds h1 (conflict-free
// lane-stride-1). 256 thr, ~36KB LDS -> 4 blocks/CU.
__global__ __launch_bounds__(256, 4) void k_mlp_fwd(
    const float* __restrict__ pts,
    const float* __restrict__ W1, const float* __restrict__ b1,
    const float* __restrict__ W2, const float* __restrict__ b2,
    const float* __restrict__ W3, const float* __restrict__ b3,
    float* __restrict__ sdf_out){
  __shared__ float sH[HID*TP];    // h1 [k][p]  (32 KB)
  __shared__ float sRed[4*TP];
  const int tid = threadIdx.x;
  const int p   = tid & 63;
  const int wv  = __builtin_amdgcn_readfirstlane(tid >> 6);
  const int k0  = wv * 32;        // this wave's k-rows (layer1) / neurons (layer2)
  const int q0  = blockIdx.x * TP;
  const float x0 = pts[(q0+p)*3+0];
  const float x1 = pts[(q0+p)*3+1];
  const float x2 = pts[(q0+p)*3+2];
  // layer 1 (scalar W1/b1)
  #pragma unroll
  for (int kk = 0; kk < 32; kk++){
    int k = k0 + kk;
    float pre = b1[k];
    pre = fmaf(x0, W1[k],       pre);
    pre = fmaf(x1, W1[HID+k],   pre);
    pre = fmaf(x2, W1[2*HID+k], pre);
    sH[k*TP + p] = sp_f(pre);
  }
  __syncthreads();
  // layer 2: wave's 32 neurons, scalar W2 rows
  float acc[32];
  #pragma unroll
  for (int j = 0; j < 32; j++) acc[j] = b2[k0+j];
  #pragma unroll 2
  for (int k = 0; k < HID; k++){
    const float hv = sH[k*TP + p];
    const float* __restrict__ wr = &W2[k*HID + k0];
    #pragma unroll
    for (int j = 0; j < 32; j++) acc[j] = fmaf(hv, wr[j], acc[j]);
  }
  // layer 3 partials (scalar W3)
  float part = 0.0f;
  #pragma unroll
  for (int j = 0; j < 32; j++) part += sp_f(acc[j]) * W3[k0+j];
  sRed[wv*TP + p] = part;
  __syncthreads();
  if (tid < TP)
    sdf_out[q0+tid] = b3[0] + sRed[tid] + sRed[TP+tid] + sRed[2*TP+tid] + sRed[3*TP+tid];
}

// ---------------------------------------------------------------- scatters
__global__ void k_scatter_init(const float* __restrict__ sdf_tmp, float* __restrict__ sdf_buf){
  int idx = blockIdx.x*256 + threadIdx.x;
  if (idx >= NRAYS*64) return;
  sdf_buf[(idx >> 6)*128 + (idx & 63)] = sdf_tmp[idx];
}
__global__ void k_scatter_new(const float* __restrict__ sdf_tmp, const int* __restrict__ slots,
                              float* __restrict__ sdf_buf){
  int idx = blockIdx.x*256 + threadIdx.x;
  if (idx >= NRAYS*16) return;
  sdf_buf[(idx >> 4)*128 + slots[idx]] = sdf_tmp[idx];
}

// ---------------------------------------------------------------- upsample (one wave per ray)
__global__ __launch_bounds__(64) void k_upsample(
      const float* __restrict__ rays_o, const float* __restrict__ rays_d,
      float* __restrict__ z_buf, float* __restrict__ sdf_buf,
      float* __restrict__ pts_new, int* __restrict__ slots,
      int S, float inv_s, int last){
  __shared__ float z[128], sd[128], rad[128], cosv[128], alf[128], wv[128], cdf[129], nz[16];
  __shared__ int slt[16];
  const int ray = blockIdx.x;
  const int l   = threadIdx.x;
  const float ox = rays_o[ray*3], oy = rays_o[ray*3+1], oz = rays_o[ray*3+2];
  const float dx = rays_d[ray*3], dy = rays_d[ray*3+1], dz = rays_d[ray*3+2];
  for (int j = l; j < S; j += 64){
    float zz = z_buf[ray*128+j];
    z[j]  = zz;
    sd[j] = sdf_buf[ray*128+j];
    float px = ox+dx*zz, py = oy+dy*zz, pz = oz+dz*zz;
    rad[j] = sqrtf(px*px + py*py + pz*pz);
  }
  __syncthreads();
  for (int j = l; j < S-1; j += 64)
    cosv[j] = (sd[j+1]-sd[j]) / (z[j+1]-z[j] + 1e-5f);
  __syncthreads();
  for (int j = l; j < S-1; j += 64){
    float cv = fminf((j > 0) ? cosv[j-1] : 0.0f, cosv[j]);
    cv = fminf(fmaxf(cv, -1000.0f), 0.0f);
    float inside = (rad[j] < 1.0f || rad[j+1] < 1.0f) ? 1.0f : 0.0f;
    cv *= inside;
    float mid  = 0.5f*(sd[j]+sd[j+1]);
    float dist = z[j+1]-z[j];
    float e = sg_f((mid - cv*dist*0.5f)*inv_s);
    float f = sg_f((mid + cv*dist*0.5f)*inv_s);
    alf[j] = (e - f + 1e-5f) / (e + 1e-5f);
  }
  __syncthreads();
  if (l == 0){
    float T = 1.0f, wsum = 0.0f;
    for (int j = 0; j < S-1; j++){
      float w = alf[j]*T + 1e-5f;   // weights = alpha*trans + 1e-5
      wv[j] = w; wsum += w;
      T *= (1.0f - alf[j] + 1e-7f);
    }
    cdf[0] = 0.0f;
    float c = 0.0f;
    for (int j = 0; j < S-1; j++){ c += wv[j]/wsum; cdf[j+1] = c; }
  }
  __syncthreads();
  if (l < 16){
    float u = 0.03125f + 0.0625f*(float)l;   // linspace(1/32, 31/32, 16)
    int idx = 0;
    while (idx < S && cdf[idx] <= u) idx++;  // searchsorted side='right'
    int below = idx - 1; if (below < 0) below = 0;
    int above = (idx < S-1) ? idx : (S-1);
    float cb = cdf[below], ca = cdf[above];
    float den = ca - cb; if (den < 1e-5f) den = 1.0f;
    float t = (u - cb) / den;
    nz[l] = z[below] + t*(z[above] - z[below]);
  }
  __syncthreads();
  if (l == 0){
    // stable in-place merge from the back (old-before-new on ties)
    int i = S-1, j = 15;
    for (int dst = S+15; dst >= 0; --dst){
      bool takeOld = (j < 0) || (i >= 0 && z[i] > nz[j]);
      if (takeOld){ z[dst] = z[i]; sd[dst] = sd[i]; i--; }
      else        { z[dst] = nz[j]; slt[j] = dst; j--; }
    }
  }
  __syncthreads();
  for (int j = l; j < S+16; j += 64){
    z_buf[ray*128+j]  = z[j];
    sdf_buf[ray*128+j] = sd[j];
  }
  if (!last && l < 16){
    slots[ray*16+l] = slt[l];
    float zz = nz[l];
    pts_new[(ray*16+l)*3+0] = ox + dx*zz;
    pts_new[(ray*16+l)*3+1] = oy + dy*zz;
    pts_new[(ray*16+l)*3+2] = oz + dz*zz;
  }
}

// ---------------------------------------------------------------- final mid-point pts
__global__ void k_prep(const float* __restrict__ rays_o, const float* __restrict__ rays_d,
                       const float* __restrict__ z_buf, float* __restrict__ pts){
  int idx = blockIdx.x*256 + threadIdx.x;
  if (idx >= NRAYS*128) return;
  int ray = idx >> 7, s = idx & 127;
  float z = z_buf[idx];
  float d = (s < 127) ? (z_buf[idx+1] - z) : 0.03125f;   // SAMPLE_DIST = 2/64
  float mid = z + 0.5f*d;
  pts[idx*3+0] = rays_o[ray*3+0] + rays_d[ray*3+0]*mid;
  pts[idx*3+1] = rays_o[ray*3+1] + rays_d[ray*3+1]*mid;
  pts[idx*3+2] = rays_o[ray*3+2] + rays_d[ray*3+2]*mid;
}

// ---------------------------------------------------------------- MLP forward + input-gradient
// Same wave-uniform tiling. Phase A: fwd (neurons per wave). sH swaps h1 -> g2
// between barriers. Phase C: dh1 (k-rows per wave) via scalar W2T rows, then
// grad = W1 @ (dh1 * sig(pre1)) with pre1 recomputed from x in registers.
__global__ __launch_bounds__(256, 4) void k_mlp_fwdbwd(
    const float* __restrict__ pts,
    const float* __restrict__ W1, const float* __restrict__ b1,
    const float* __restrict__ W2, const float* __restrict__ b2,
    const float* __restrict__ W3, const float* __restrict__ b3,
    const float* __restrict__ W2T,
    float* __restrict__ sdf_out, float* __restrict__ grad_out){
  __shared__ float sH[HID*TP];    // h1 in phase A, g2 in phase C (32 KB)
  __shared__ float sRed[4*TP];    // sdf partials
  __shared__ float sGx[4*TP], sGy[4*TP], sGz[4*TP];
  const int tid = threadIdx.x;
  const int p   = tid & 63;
  const int wv  = __builtin_amdgcn_readfirstlane(tid >> 6);
  const int k0  = wv * 32;
  const int q0  = blockIdx.x * TP;
  const float x0 = pts[(q0+p)*3+0];
  const float x1 = pts[(q0+p)*3+1];
  const float x2 = pts[(q0+p)*3+2];
  // layer 1
  #pragma unroll
  for (int kk = 0; kk < 32; kk++){
    int k = k0 + kk;
    float pre = b1[k];
    pre = fmaf(x0, W1[k],       pre);
    pre = fmaf(x1, W1[HID+k],   pre);
    pre = fmaf(x2, W1[2*HID+k], pre);
    sH[k*TP + p] = sp_f(pre);
  }
  __syncthreads();
  // phase A: layer 2 forward, wave's 32 neurons
  float acc[32];
  #pragma unroll
  for (int j = 0; j < 32; j++) acc[j] = b2[k0+j];
  #pragma unroll 2
  for (int k = 0; k < HID; k++){
    const float hv = sH[k*TP + p];
    const float* __restrict__ wr = &W2[k*HID + k0];
    #pragma unroll
    for (int j = 0; j < 32; j++) acc[j] = fmaf(hv, wr[j], acc[j]);
  }
  // sdf partials (scalar W3)
  {
    float part = 0.0f;
    #pragma unroll
    for (int j = 0; j < 32; j++) part += sp_f(acc[j]) * W3[k0+j];
    sRed[wv*TP + p] = part;
  }
  __syncthreads();   // all waves done reading h1
  // overwrite sH with g2 = sigmoid(pre2) * W3  (lane-stride-1, conflict-free)
  #pragma unroll
  for (int j = 0; j < 32; j++)
    sH[(k0+j)*TP + p] = sg_f(acc[j]) * W3[k0+j];
  __syncthreads();
  // phase C: dh1[k] = sum_n g2[n] * W2T[n][k], wave's 32 k-rows
  float accD[32];
  #pragma unroll
  for (int j = 0; j < 32; j++) accD[j] = 0.0f;
  #pragma unroll 2
  for (int n = 0; n < HID; n++){
    const float gv = sH[n*TP + p];
    const float* __restrict__ wr = &W2T[n*HID + k0];
    #pragma unroll
    for (int j = 0; j < 32; j++) accD[j] = fmaf(gv, wr[j], accD[j]);
  }
  // dp1 = dh1 * sigmoid(pre1); grad partials = W1 @ dp1 (scalar W1)
  {
    float gxa = 0.f, gya = 0.f, gza = 0.f;
    #pragma unroll
    for (int j = 0; j < 32; j++){
      int k = k0 + j;
      float w1a = W1[k], w1b = W1[HID+k], w1c = W1[2*HID+k];
      float pre1 = b1[k];
      pre1 = fmaf(x0, w1a, pre1);
      pre1 = fmaf(x1, w1b, pre1);
      pre1 = fmaf(x2, w1c, pre1);
      float d = accD[j] * sg_f(pre1);
      gxa = fmaf(w1a, d, gxa); gya = fmaf(w1b, d, gya); gza = fmaf(w1c, d, gza);
    }
    sGx[wv*TP + p] = gxa; sGy[wv*TP + p] = gya; sGz[wv*TP + p] = gza;
  }
  __syncthreads();
  if (tid < TP){
    sdf_out[q0+tid] = b3[0] + sRed[tid] + sRed[TP+tid] + sRed[2*TP+tid] + sRed[3*TP+tid];
    float gx = sGx[tid] + sGx[TP+tid] + sGx[2*TP+tid] + sGx[3*TP+tid];
    float gy = sGy[tid] + sGy[TP+tid] + sGy[2*TP+tid] + sGy[3*TP+tid];
    float gz = sGz[tid] + sGz[TP+tid] + sGz[2*TP+tid] + sGz[3*TP+tid];
    grad_out[(q0+tid)*3+0] = gx;
    grad_out[(q0+tid)*3+1] = gy;
    grad_out[(q0+tid)*3+2] = gz;
  }
}

// ---------------------------------------------------------------- render (one thread per ray)
__global__ void k_render(const float* __restrict__ z_buf, const float* __restrict__ sdf_mid,
                         const float* __restrict__ rays_d, const float* __restrict__ grad,
                         const float* __restrict__ variance, float* __restrict__ depth_out){
  int ray = blockIdx.x*64 + threadIdx.x;
  if (ray >= NRAYS) return;
  float inv_s = expf(10.0f * variance[0]);
  inv_s = fminf(fmaxf(inv_s, 1e-6f), 1e6f);
  const float dx = rays_d[ray*3], dy = rays_d[ray*3+1], dz = rays_d[ray*3+2];
  float T = 1.0f, depth = 0.0f;
  float zc = z_buf[ray*128];
  for (int s = 0; s < 128; s++){
    int idx = ray*128 + s;
    float zn = (s < 127) ? z_buf[idx+1] : zc;
    float d  = (s < 127) ? (zn - zc) : 0.03125f;
    float sdf = sdf_mid[idx];
    float gx = grad[idx*3], gy = grad[idx*3+1], gz = grad[idx*3+2];
    float tc = dx*gx + dy*gy + dz*gz;
    float ic = -fmaxf(0.5f - 0.5f*tc, 0.0f);     // COS_ANNEAL_RATIO = 0
    float e = sg_f((sdf - ic*d*0.5f)*inv_s);
    float f = sg_f((sdf + ic*d*0.5f)*inv_s);
    float a = (e - f + 1e-5f) / (e + 1e-5f);
    a = fminf(fmaxf(a, 0.0f), 1.0f);
    depth += a*T*zc;
    T *= (1.0f - a + 1e-7f);
    zc = zn;
  }
  depth_out[ray] = depth;
}

// ---------------------------------------------------------------- launcher
extern "C" void kernel_launch(void* const* d_in, const int* in_sizes, int n_in,
                              void* d_out, int out_size, void* d_ws, size_t ws_size,
                              hipStream_t stream){
  (void)in_sizes; (void)n_in; (void)out_size; (void)ws_size;
  const float* rays_o = (const float*)d_in[0];
  const float* rays_d = (const float*)d_in[1];
  const float* nearv  = (const float*)d_in[2];
  const float* farv   = (const float*)d_in[3];
  const float* W1 = (const float*)d_in[4];
  const float* b1 = (const float*)d_in[5];
  const float* W2 = (const float*)d_in[6];
  const float* b2 = (const float*)d_in[7];
  const float* W3 = (const float*)d_in[8];
  const float* b3 = (const float*)d_in[9];
  const float* variance = (const float*)d_in[10];

  float* ws      = (float*)d_ws;
  float* z_buf   = ws;                    // 4096*128
  float* sdf_buf = ws + 524288;           // 4096*128
  float* sdf_tmp = ws + 1048576;          // up to 524288
  float* W2T     = ws + 1572864;          // 16384
  int*   slots   = (int*)(ws + 1589248);  // 4096*16 ints

  float* out       = (float*)d_out;
  float* depth_out = out;
  float* grad_out  = out + NRAYS;         // 524288*3 floats
  float* pts       = grad_out;            // alias: pts staging lives in the grad region

  k_transpose<<<dim3(64), dim3(256), 0, stream>>>(W2, W2T);
  k_init<<<dim3(1024), dim3(256), 0, stream>>>(rays_o, rays_d, nearv, farv, z_buf, pts);
  k_mlp_fwd<<<dim3(4096), dim3(256), 0, stream>>>(pts, W1,b1,W2,b2,W3,b3, sdf_tmp);
  k_scatter_init<<<dim3(1024), dim3(256), 0, stream>>>(sdf_tmp, sdf_buf);

  for (int i = 0; i < 4; i++){
    int S = 64 + 16*i;
    float inv_s = (float)(64 << i);
    int last = (i == 3) ? 1 : 0;
    k_upsample<<<dim3(4096), dim3(64), 0, stream>>>(rays_o, rays_d, z_buf, sdf_buf,
                                                    pts, slots, S, inv_s, last);
    if (!last){
      k_mlp_fwd<<<dim3(1024), dim3(256), 0, stream>>>(pts, W1,b1,W2,b2,W3,b3, sdf_tmp);
      k_scatter_new<<<dim3(256), dim3(256), 0, stream>>>(sdf_tmp, slots, sdf_buf);
    }
  }

  k_prep<<<dim3(2048), dim3(256), 0, stream>>>(rays_o, rays_d, z_buf, pts);
  k_mlp_fwdbwd<<<dim3(8192), dim3(256), 0, stream>>>(pts, W1,b1,W2,b2,W3,b3, W2T,
                                                     sdf_tmp, grad_out);
  k_render<<<dim3(64), dim3(64), 0, stream>>>(z_buf, sdf_tmp, rays_d, grad_out,
                                              variance, depth_out);
}